// Round 6
// baseline (285.004 us; speedup 1.0000x reference)
//
#include <hip/hip_runtime.h>

// CenterShift: out[n,o] = x[n] * (celu(celu((pos_j-pos_i)@w11+b11)@w12+b12) @ w13 + b13)[o]
// N = 2097152, dims 3 -> 16 -> 64 -> 64, fp32 in/out.
//
// Round 6 = round 5 with a VGPR diet targeting <=128 (the 4-waves/SIMD bucket):
//  - b12 bias injected via layer-2's spare K slot (k=16): kills b2v registers
//  - a3 (w13^T fragments) gathered AFTER the layer-1/2 phase, behind a memory
//    fence: live ranges split, peak pressure = max(phases) not sum
//  - b13 bias + x loaded fresh in the epilogue (L1-resident, 1 line each)
//  - otherwise identical to r5: per-wave 64-pt tile, mfma_f32_16x16x32_f16
//    for layers 2+3 (swapped operands D[o,p], layouts numerically proven
//    r2-r5), XOR-swizzled 8KB/wave h2 tile, direct full-sector stores,
//    no __syncthreads.

typedef __attribute__((ext_vector_type(8))) _Float16 f16x8;
typedef __attribute__((ext_vector_type(4))) float f32x4;

__device__ __forceinline__ float celu1(float a) {
    return a > 0.0f ? a : __expf(a) - 1.0f;
}

__global__ __launch_bounds__(256) void centershift_kernel(
    const float* __restrict__ x,
    const float* __restrict__ pos_i,
    const float* __restrict__ pos_j,
    const float* __restrict__ w11, const float* __restrict__ b11,
    const float* __restrict__ w12, const float* __restrict__ b12,
    const float* __restrict__ w13, const float* __restrict__ b13,
    float* __restrict__ out, int n)
{
    __shared__ __align__(16) _Float16 h2s[4][64 * 64];  // 8 KB/wave, swizzled

    const int lane = threadIdx.x & 63;
    const int wid  = threadIdx.x >> 6;
    const int g    = lane >> 4;    // 16-lane group 0..3
    const int r16  = lane & 15;
    const int swz  = (r16 & 7) << 4;

    const int tb = (blockIdx.x * 4 + wid) * 64;   // 64 points per wave
    if (tb >= n) return;

    char* h2b = (char*)&h2s[wid][0];

    // ---- phase A fragments: layer-2 A = w12^T, K padded 16->32 with bias row ----
    // A[row = u2*16 + r16][k = g*8 + j]; k==16 slot carries b12[row].
    f16x8 a2[4];
#pragma unroll
    for (int u2 = 0; u2 < 4; ++u2) {
        f16x8 v;
#pragma unroll
        for (int j = 0; j < 8; ++j) {
            const int k = g * 8 + j;
            v[j] = (k < 16) ? (_Float16)w12[k * 64 + u2 * 16 + r16]
                 : (k == 16) ? (_Float16)b12[u2 * 16 + r16]
                 : (_Float16)0.0f;
        }
        a2[u2] = v;
    }

    // ---- layers 1+2: four 16-point column tiles -> swizzled LDS ----
#pragma unroll
    for (int t = 0; t < 4; ++t) {
        const int pt = t * 16 + r16;
        const int q  = tb + pt;
        const float3 pi = *reinterpret_cast<const float3*>(pos_i + 3 * (size_t)q);
        const float3 pj = *reinterpret_cast<const float3*>(pos_j + 3 * (size_t)q);
        const float p0 = pj.x - pi.x, p1 = pj.y - pi.y, p2 = pj.z - pi.z;

        // B[k = g*8+j][col = r16]: g<2 carry h1 halves; g==2,j==0 carries 1.0
        const int ch0 = (g & 1) * 8;
        f16x8 b2f;
#pragma unroll
        for (int j = 0; j < 8; ++j) {
            const int c = ch0 + j;
            float a = b11[c];
            a = fmaf(p0, w11[c], a);
            a = fmaf(p1, w11[16 + c], a);
            a = fmaf(p2, w11[32 + c], a);
            a = celu1(a);
            b2f[j] = (g < 2) ? (_Float16)a
                   : (g == 2 && j == 0) ? (_Float16)1.0f
                   : (_Float16)0.0f;
        }
#pragma unroll
        for (int u2 = 0; u2 < 4; ++u2) {
            f32x4 acc = { 0.0f, 0.0f, 0.0f, 0.0f };
            acc = __builtin_amdgcn_mfma_f32_16x16x32_f16(a2[u2], b2f, acc, 0, 0, 0);
            union { _Float16 h[4]; unsigned long long v; } pk;
            pk.h[0] = (_Float16)celu1(acc[0]);
            pk.h[1] = (_Float16)celu1(acc[1]);
            pk.h[2] = (_Float16)celu1(acc[2]);
            pk.h[3] = (_Float16)celu1(acc[3]);
            // h2[pt][ch = u2*16 + g*4 + 0..3], byte = pt*128 + ch*2, swizzled
            const int byteoff = pt * 128 + u2 * 32 + g * 8;
            *reinterpret_cast<unsigned long long*>(h2b + (byteoff ^ swz)) = pk.v;
        }
    }

    // live-range split: keep the w13 gathers out of the high-pressure phase
    asm volatile("" ::: "memory");

    // ---- phase B fragments: layer-3 A = w13^T ----
    // A[row = u*16 + r16][k = kh*32 + g*8 + j]
    f16x8 a3[4][2];
#pragma unroll
    for (int u = 0; u < 4; ++u)
#pragma unroll
        for (int kh = 0; kh < 2; ++kh) {
            f16x8 v;
#pragma unroll
            for (int j = 0; j < 8; ++j)
                v[j] = (_Float16)w13[(kh * 32 + g * 8 + j) * 64 + u * 16 + r16];
            a3[u][kh] = v;
        }

    // ---- layer 3: MFMA + direct full-sector stores ----
#pragma unroll
    for (int t2 = 0; t2 < 4; ++t2) {
        const int pt = t2 * 16 + r16;
        const f16x8 bb0 = *reinterpret_cast<const f16x8*>(h2b + ((pt * 128 +      g * 16) ^ swz));
        const f16x8 bb1 = *reinterpret_cast<const f16x8*>(h2b + ((pt * 128 + 64 + g * 16) ^ swz));
        const float xvt = x[tb + pt];              // 1 line, L1 broadcast
        float* optr = out + (size_t)(tb + pt) * 64;
#pragma unroll
        for (int u = 0; u < 4; ++u) {
            // bias for o = u*16 + g*4 + {0..3}: one 16B load, one line per u
            const float4 bias = *reinterpret_cast<const float4*>(b13 + u * 16 + g * 4);
            f32x4 acc = { bias.x, bias.y, bias.z, bias.w };
            acc = __builtin_amdgcn_mfma_f32_16x16x32_f16(a3[u][0], bb0, acc, 0, 0, 0);
            acc = __builtin_amdgcn_mfma_f32_16x16x32_f16(a3[u][1], bb1, acc, 0, 0, 0);
            float4 o4 = { acc[0] * xvt, acc[1] * xvt, acc[2] * xvt, acc[3] * xvt };
            *reinterpret_cast<float4*>(optr + u * 16 + g * 4) = o4;
        }
    }
}

extern "C" void kernel_launch(void* const* d_in, const int* in_sizes, int n_in,
                              void* d_out, int out_size, void* d_ws, size_t ws_size,
                              hipStream_t stream) {
    const float* x     = (const float*)d_in[0];
    const float* pos_i = (const float*)d_in[1];
    const float* pos_j = (const float*)d_in[2];
    const float* w11   = (const float*)d_in[3];
    const float* b11   = (const float*)d_in[4];
    const float* w12   = (const float*)d_in[5];
    const float* b12   = (const float*)d_in[6];
    const float* w13   = (const float*)d_in[7];
    const float* b13   = (const float*)d_in[8];
    float* out = (float*)d_out;

    const int n = in_sizes[0];                 // N (x is [N,1])
    const int blocks = (n + 255) / 256;        // 4 waves/block, 64 points/wave
    centershift_kernel<<<blocks, 256, 0, stream>>>(
        x, pos_i, pos_j, w11, b11, w12, b12, w13, b13, out, n);
}

// Round 7
// 203.392 us; speedup vs baseline: 1.4013x; 1.4013x over previous
//
#include <hip/hip_runtime.h>

// CenterShift: out[n,o] = x[n] * (celu(celu((pos_j-pos_i)@w11+b11)@w12+b12) @ w13 + b13)[o]
// N = 2097152, dims 3 -> 16 -> 64 -> 64, fp32 in/out.
//
// Round 7 = round 2's structure (the measured best: scalar layer-2, pos loaded
// ONCE per lane for its own point, one 64-pt tile per wave, direct full-sector
// stores) + occupancy levers only:
//  - compact XOR-swizzled h2 tile: 8 KB/wave (32 KB/block -> 5 blocks/CU vs
//    r2's 36.9 KB -> 4). Swizzle byte ^= (row&7)<<4; write row = lane, read
//    row = pt (pt&7 == r16&7). 8 bank-groups x 8 lanes -> conflict-free b128.
//  - a3 (w13^T) gathered AFTER the layer-1/2 phase behind a compiler fence
//    (live-range split, r6-proven); b13 loaded as float4 in the epilogue.
//  - x loaded directly in epilogue (no __shfl -> no ds_bpermute LDS traffic).
// Goal: VGPR <= ~100, 20 waves/CU, to hide the per-wave serial chain under
// more TLP. MFMA layer-2 variants (r3/r5/r6) all measured WORSE than scalar.

typedef __attribute__((ext_vector_type(8))) _Float16 f16x8;
typedef __attribute__((ext_vector_type(4))) float f32x4;

__device__ __forceinline__ float celu1(float a) {
    return a > 0.0f ? a : __expf(a) - 1.0f;
}

__global__ __launch_bounds__(256) void centershift_kernel(
    const float* __restrict__ x,
    const float* __restrict__ pos_i,
    const float* __restrict__ pos_j,
    const float* __restrict__ w11, const float* __restrict__ b11,
    const float* __restrict__ w12, const float* __restrict__ b12,
    const float* __restrict__ w13, const float* __restrict__ b13,
    float* __restrict__ out, int n)
{
    __shared__ __align__(16) _Float16 h2s[4][64 * 64];  // 8 KB/wave, swizzled

    const int lane = threadIdx.x & 63;
    const int wid  = threadIdx.x >> 6;
    const int g    = lane >> 4;    // 16-lane group 0..3
    const int r16  = lane & 15;

    const int tb = (blockIdx.x * 4 + wid) * 64;   // 64 points per wave
    if (tb >= n) return;
    const int p = tb + lane;

    char* h2b = (char*)&h2s[wid][0];

    // ---- layer 1: 3 -> 16 (lane = its own point; weights wave-uniform) ----
    const float3 pi = *reinterpret_cast<const float3*>(pos_i + 3 * (size_t)p);
    const float3 pj = *reinterpret_cast<const float3*>(pos_j + 3 * (size_t)p);
    const float p0 = pj.x - pi.x, p1 = pj.y - pi.y, p2 = pj.z - pi.z;

    float h1[16];
#pragma unroll
    for (int j = 0; j < 16; ++j) {
        float a = b11[j];
        a = fmaf(p0, w11[j], a);
        a = fmaf(p1, w11[16 + j], a);
        a = fmaf(p2, w11[32 + j], a);
        h1[j] = celu1(a);
    }

    // ---- layer 2: 16 -> 64 scalar, streamed to swizzled LDS in f16x8 chunks ----
    // write row = lane: byte = lane*128 + c*16, swizzled by (lane&7)<<4
    const int swzW = (lane & 7) << 4;
    const int rowW = lane * 128;
    for (int c = 0; c < 8; ++c) {
        f16x8 v;
#pragma unroll
        for (int j = 0; j < 8; ++j) {
            const int o = c * 8 + j;
            float a = b12[o];
#pragma unroll
            for (int k = 0; k < 16; ++k)
                a = fmaf(h1[k], w12[k * 64 + o], a);
            v[j] = (_Float16)celu1(a);
        }
        *reinterpret_cast<f16x8*>(h2b + (rowW + ((c * 16) ^ swzW))) = v;
    }

    // live-range split: keep the w13 gathers out of the high-pressure phase
    asm volatile("" ::: "memory");

    // ---- layer-3 A fragments = w13^T: A[row = u*16 + r16][k = kh*32 + g*8 + j] ----
    f16x8 a3[4][2];
#pragma unroll
    for (int u = 0; u < 4; ++u)
#pragma unroll
        for (int kh = 0; kh < 2; ++kh) {
            f16x8 v;
#pragma unroll
            for (int j = 0; j < 8; ++j)
                v[j] = (_Float16)w13[(kh * 32 + g * 8 + j) * 64 + u * 16 + r16];
            a3[u][kh] = v;
        }

    // ---- layer 3: MFMA (swapped operands D[o,p]) + direct full-sector stores ----
    const int swzR = (r16 & 7) << 4;
#pragma unroll
    for (int t2 = 0; t2 < 4; ++t2) {
        const int pt   = t2 * 16 + r16;
        const int rowR = pt * 128;
        const f16x8 bb0 = *reinterpret_cast<const f16x8*>(h2b + (rowR + ((     g * 16) ^ swzR)));
        const f16x8 bb1 = *reinterpret_cast<const f16x8*>(h2b + (rowR + ((64 + g * 16) ^ swzR)));
        const float xvt = x[tb + pt];              // 1 line, L1 broadcast
        float* optr = out + (size_t)(tb + pt) * 64;
#pragma unroll
        for (int u = 0; u < 4; ++u) {
            const float4 bias = *reinterpret_cast<const float4*>(b13 + u * 16 + g * 4);
            f32x4 acc = { bias.x, bias.y, bias.z, bias.w };
            acc = __builtin_amdgcn_mfma_f32_16x16x32_f16(a3[u][0], bb0, acc, 0, 0, 0);
            acc = __builtin_amdgcn_mfma_f32_16x16x32_f16(a3[u][1], bb1, acc, 0, 0, 0);
            // lane holds out channels o = u*16 + g*4 + {0..3} of point tb+pt
            float4 o4 = { acc[0] * xvt, acc[1] * xvt, acc[2] * xvt, acc[3] * xvt };
            *reinterpret_cast<float4*>(optr + u * 16 + g * 4) = o4;
        }
    }
}

extern "C" void kernel_launch(void* const* d_in, const int* in_sizes, int n_in,
                              void* d_out, int out_size, void* d_ws, size_t ws_size,
                              hipStream_t stream) {
    const float* x     = (const float*)d_in[0];
    const float* pos_i = (const float*)d_in[1];
    const float* pos_j = (const float*)d_in[2];
    const float* w11   = (const float*)d_in[3];
    const float* b11   = (const float*)d_in[4];
    const float* w12   = (const float*)d_in[5];
    const float* b12   = (const float*)d_in[6];
    const float* w13   = (const float*)d_in[7];
    const float* b13   = (const float*)d_in[8];
    float* out = (float*)d_out;

    const int n = in_sizes[0];                 // N (x is [N,1])
    const int blocks = (n + 255) / 256;        // 4 waves/block, 64 points/wave
    centershift_kernel<<<blocks, 256, 0, stream>>>(
        x, pos_i, pos_j, w11, b11, w12, b12, w13, b13, out, n);
}

// Round 8
// 193.075 us; speedup vs baseline: 1.4761x; 1.0534x over previous
//
#include <hip/hip_runtime.h>

// CenterShift: out[n,o] = x[n] * (celu(celu((pos_j-pos_i)@w11+b11)@w12+b12) @ w13 + b13)[o]
// N = 2097152, dims 3 -> 16 -> 64 -> 64, fp32 in/out.
//
// Round 8 = r2's compute structure + software-pipelined 4-tile wave loop.
// Theory: one-shot waves cluster into compute-phase / store-burst generations
// (HBM idle during compute, saturated during bursts -> 2x effective write
// time). The fill kernel proves stores saturate HBM at <1 wave/SIMD, so a
// per-wave tile loop whose fire-and-forget stores drain during the NEXT
// tile's ~2500cy compute restores a steady state.
//  - gathers (a3, b3v) hoisted FIRST, no fences (r7's fence was a regression)
//  - scalar layer-2, lane = own point (r2 winner; MFMA-l2 lost 3 times)
//  - compact XOR-swizzled 8 KB/wave h2 tile (write row=lane, read row=pt;
//    numerics verified r7)
//  - direct full-sector stores (16B/lane, 4 lane-groups cover contiguous 64B
//    per point); next-tile pos prefetched right after h1 consumes current
//  - no __syncthreads; per-wave LDS; DS pipe in-order per wave -> WAR-safe

typedef __attribute__((ext_vector_type(8))) _Float16 f16x8;
typedef __attribute__((ext_vector_type(4))) float f32x4;

#define TILES 4

__device__ __forceinline__ float celu1(float a) {
    return a > 0.0f ? a : __expf(a) - 1.0f;
}

__global__ __launch_bounds__(256) void centershift_kernel(
    const float* __restrict__ x,
    const float* __restrict__ pos_i,
    const float* __restrict__ pos_j,
    const float* __restrict__ w11, const float* __restrict__ b11,
    const float* __restrict__ w12, const float* __restrict__ b12,
    const float* __restrict__ w13, const float* __restrict__ b13,
    float* __restrict__ out, int n)
{
    __shared__ __align__(16) _Float16 h2s[4][64 * 64];  // 8 KB/wave, swizzled

    const int lane = threadIdx.x & 63;
    const int wid  = threadIdx.x >> 6;
    const int g    = lane >> 4;    // 16-lane group 0..3
    const int r16  = lane & 15;

    const int wbase = (blockIdx.x * 4 + wid) * (64 * TILES);
    if (wbase >= n) return;

    char* h2b = (char*)&h2s[wid][0];

    // ---- hoisted fragments: issue these loads FIRST (overlap tile-0 compute) ----
    // layer-3 A = w13^T: A[row = u*16 + r16][k = kh*32 + g*8 + j]
    f16x8 a3[4][2];
#pragma unroll
    for (int u = 0; u < 4; ++u)
#pragma unroll
        for (int kh = 0; kh < 2; ++kh) {
            f16x8 v;
#pragma unroll
            for (int j = 0; j < 8; ++j)
                v[j] = (_Float16)w13[(kh * 32 + g * 8 + j) * 64 + u * 16 + r16];
            a3[u][kh] = v;
        }
    // bias in C/D layout: lane holds o = u*16 + g*4 + rr
    float b3v[4][4];
#pragma unroll
    for (int u = 0; u < 4; ++u) {
        const float4 bv = *reinterpret_cast<const float4*>(b13 + u * 16 + g * 4);
        b3v[u][0] = bv.x; b3v[u][1] = bv.y; b3v[u][2] = bv.z; b3v[u][3] = bv.w;
    }

    // ---- preload tile-0 pos (lane = its own point) ----
    const float* pip = pos_i + 3 * (size_t)(wbase + lane);
    const float* pjp = pos_j + 3 * (size_t)(wbase + lane);
    float3 cpi = *reinterpret_cast<const float3*>(pip);
    float3 cpj = *reinterpret_cast<const float3*>(pjp);

    const int swzW = (lane & 7) << 4;
    const int rowW = lane * 128;
    const int swzR = (r16 & 7) << 4;

#pragma unroll 1
    for (int t = 0; t < TILES; ++t) {
        const int tb = wbase + t * 64;
        if (tb >= n) break;

        const float p0 = cpj.x - cpi.x, p1 = cpj.y - cpi.y, p2 = cpj.z - cpi.z;

        // ---- layer 1: 3 -> 16 ----
        float h1[16];
#pragma unroll
        for (int j = 0; j < 16; ++j) {
            float a = b11[j];
            a = fmaf(p0, w11[j], a);
            a = fmaf(p1, w11[16 + j], a);
            a = fmaf(p2, w11[32 + j], a);
            h1[j] = celu1(a);
        }

        // prefetch next tile's pos: ~2500cy of compute below hides the latency
        if (t + 1 < TILES) {
            cpi = *reinterpret_cast<const float3*>(pip + (t + 1) * 192);
            cpj = *reinterpret_cast<const float3*>(pjp + (t + 1) * 192);
        }

        // ---- layer 2: 16 -> 64 scalar (wave-uniform weights -> s_load),
        //      streamed to swizzled LDS in f16x8 chunks ----
        for (int c = 0; c < 8; ++c) {
            f16x8 v;
#pragma unroll
            for (int j = 0; j < 8; ++j) {
                const int o = c * 8 + j;
                float a = b12[o];
#pragma unroll
                for (int k = 0; k < 16; ++k)
                    a = fmaf(h1[k], w12[k * 64 + o], a);
                v[j] = (_Float16)celu1(a);
            }
            *reinterpret_cast<f16x8*>(h2b + (rowW + ((c * 16) ^ swzW))) = v;
        }

        // ---- layer 3: MFMA (swapped operands D[o,p]) + direct stores ----
        // Stores are fire-and-forget; they drain during the next tile's compute.
#pragma unroll
        for (int t2 = 0; t2 < 4; ++t2) {
            const int pt   = t2 * 16 + r16;
            const int rowR = pt * 128;
            const f16x8 bb0 = *reinterpret_cast<const f16x8*>(h2b + (rowR + ((     g * 16) ^ swzR)));
            const f16x8 bb1 = *reinterpret_cast<const f16x8*>(h2b + (rowR + ((64 + g * 16) ^ swzR)));
            const float xvt = x[tb + pt];          // 1 line, L1 broadcast
            float* optr = out + (size_t)(tb + pt) * 64;
#pragma unroll
            for (int u = 0; u < 4; ++u) {
                f32x4 acc = { b3v[u][0], b3v[u][1], b3v[u][2], b3v[u][3] };
                acc = __builtin_amdgcn_mfma_f32_16x16x32_f16(a3[u][0], bb0, acc, 0, 0, 0);
                acc = __builtin_amdgcn_mfma_f32_16x16x32_f16(a3[u][1], bb1, acc, 0, 0, 0);
                // lane holds out channels o = u*16 + g*4 + {0..3} of point tb+pt
                float4 o4 = { acc[0] * xvt, acc[1] * xvt, acc[2] * xvt, acc[3] * xvt };
                *reinterpret_cast<float4*>(optr + u * 16 + g * 4) = o4;
            }
        }
    }
}

extern "C" void kernel_launch(void* const* d_in, const int* in_sizes, int n_in,
                              void* d_out, int out_size, void* d_ws, size_t ws_size,
                              hipStream_t stream) {
    const float* x     = (const float*)d_in[0];
    const float* pos_i = (const float*)d_in[1];
    const float* pos_j = (const float*)d_in[2];
    const float* w11   = (const float*)d_in[3];
    const float* b11   = (const float*)d_in[4];
    const float* w12   = (const float*)d_in[5];
    const float* b12   = (const float*)d_in[6];
    const float* w13   = (const float*)d_in[7];
    const float* b13   = (const float*)d_in[8];
    float* out = (float*)d_out;

    const int n = in_sizes[0];                        // N (x is [N,1])
    const int per_block = 256 * TILES;                // 4 waves x 4 tiles x 64 pts
    const int blocks = (n + per_block - 1) / per_block;
    centershift_kernel<<<blocks, 256, 0, stream>>>(
        x, pos_i, pos_j, w11, b11, w12, b12, w13, b13, out, n);
}

// Round 9
// 146.203 us; speedup vs baseline: 1.9494x; 1.3206x over previous
//
#include <hip/hip_runtime.h>

// CenterShift: out[n,o] = x[n] * (celu(celu((pos_j-pos_i)@w11+b11)@w12+b12) @ w13 + b13)[o]
// N = 2097152, dims 3 -> 16 -> 64 -> 64, fp32 in/out.
//
// Round 9 = r8 skeleton + CONTIGUOUS-STREAM stores via 4KB/wave LDS bounce.
// Evidence: fill kernel (contiguous 1KB/instr) = 6.5-6.8 TB/s at 3.4 waves/CU;
// r1 (64-line scatter/instr) capped at 3.6 TB/s; r2/r8 (16-line 256B-stride
// scatter/instr) ~3.0 TB/s effective. Compute is only ~40us chip-wide, so the
// store pattern is the binding constraint. This round each store instruction
// writes one contiguous 1KB chunk (fill pattern): MFMA D-layout results are
// bounced through a per-wave 4KB f32 LDS tile (XOR-swizzled, bijective:
// byte = pt*256 + ((c*16) ^ ((pt&7)<<4)) on both sides) and re-read row-major.
//  - scalar layer-2 (r2 winner), compact swizzled h2 tile (r7/r8-verified)
//  - gathers hoisted first, no fences; 4-tile loop + pos prefetch (r8)
//  - per-wave LDS only, no __syncthreads; DS in-order per wave -> WAR-safe
//    reuse of the bounce buffer across t2 groups and tiles.

typedef __attribute__((ext_vector_type(8))) _Float16 f16x8;
typedef __attribute__((ext_vector_type(4))) float f32x4;

#define TILES 4

__device__ __forceinline__ float celu1(float a) {
    return a > 0.0f ? a : __expf(a) - 1.0f;
}

__global__ __launch_bounds__(256) void centershift_kernel(
    const float* __restrict__ x,
    const float* __restrict__ pos_i,
    const float* __restrict__ pos_j,
    const float* __restrict__ w11, const float* __restrict__ b11,
    const float* __restrict__ w12, const float* __restrict__ b12,
    const float* __restrict__ w13, const float* __restrict__ b13,
    float* __restrict__ out, int n)
{
    __shared__ __align__(16) _Float16 h2s[4][64 * 64];  // 8 KB/wave, swizzled
    __shared__ __align__(16) float    stg[4][1024];     // 4 KB/wave bounce

    const int lane = threadIdx.x & 63;
    const int wid  = threadIdx.x >> 6;
    const int g    = lane >> 4;    // 16-lane group 0..3
    const int r16  = lane & 15;

    const int wbase = (blockIdx.x * 4 + wid) * (64 * TILES);
    if (wbase >= n) return;

    char* h2b  = (char*)&h2s[wid][0];
    char* stgb = (char*)&stg[wid][0];

    // ---- hoisted fragments (issue first; overlap tile-0 compute) ----
    // layer-3 A = w13^T: A[row = u*16 + r16][k = kh*32 + g*8 + j]
    f16x8 a3[4][2];
#pragma unroll
    for (int u = 0; u < 4; ++u)
#pragma unroll
        for (int kh = 0; kh < 2; ++kh) {
            f16x8 v;
#pragma unroll
            for (int j = 0; j < 8; ++j)
                v[j] = (_Float16)w13[(kh * 32 + g * 8 + j) * 64 + u * 16 + r16];
            a3[u][kh] = v;
        }
    // bias in C/D layout: lane holds o = u*16 + g*4 + rr
    float b3v[4][4];
#pragma unroll
    for (int u = 0; u < 4; ++u) {
        const float4 bv = *reinterpret_cast<const float4*>(b13 + u * 16 + g * 4);
        b3v[u][0] = bv.x; b3v[u][1] = bv.y; b3v[u][2] = bv.z; b3v[u][3] = bv.w;
    }

    // ---- preload tile-0 pos (lane = its own point) ----
    const float* pip = pos_i + 3 * (size_t)(wbase + lane);
    const float* pjp = pos_j + 3 * (size_t)(wbase + lane);
    float3 cpi = *reinterpret_cast<const float3*>(pip);
    float3 cpj = *reinterpret_cast<const float3*>(pjp);

    const int swzW = (lane & 7) << 4;
    const int rowW = lane * 128;
    const int swzR = (r16 & 7) << 4;

#pragma unroll 1
    for (int t = 0; t < TILES; ++t) {
        const int tb = wbase + t * 64;
        if (tb >= n) break;

        const float p0 = cpj.x - cpi.x, p1 = cpj.y - cpi.y, p2 = cpj.z - cpi.z;

        // ---- layer 1: 3 -> 16 ----
        float h1[16];
#pragma unroll
        for (int j = 0; j < 16; ++j) {
            float a = b11[j];
            a = fmaf(p0, w11[j], a);
            a = fmaf(p1, w11[16 + j], a);
            a = fmaf(p2, w11[32 + j], a);
            h1[j] = celu1(a);
        }

        // prefetch next tile's pos (hidden under the compute below)
        if (t + 1 < TILES) {
            cpi = *reinterpret_cast<const float3*>(pip + (t + 1) * 192);
            cpj = *reinterpret_cast<const float3*>(pjp + (t + 1) * 192);
        }

        // ---- layer 2: 16 -> 64 scalar (wave-uniform weights), to swizzled LDS ----
        for (int c = 0; c < 8; ++c) {
            f16x8 v;
#pragma unroll
            for (int j = 0; j < 8; ++j) {
                const int o = c * 8 + j;
                float a = b12[o];
#pragma unroll
                for (int k = 0; k < 16; ++k)
                    a = fmaf(h1[k], w12[k * 64 + o], a);
                v[j] = (_Float16)celu1(a);
            }
            *reinterpret_cast<f16x8*>(h2b + (rowW + ((c * 16) ^ swzW))) = v;
        }

        // ---- layer 3: MFMA -> LDS bounce -> contiguous 1KB-per-instr stores ----
#pragma unroll
        for (int t2 = 0; t2 < 4; ++t2) {
            const int pt   = t2 * 16 + r16;
            const int rowR = pt * 128;
            const f16x8 bb0 = *reinterpret_cast<const f16x8*>(h2b + (rowR + ((     g * 16) ^ swzR)));
            const f16x8 bb1 = *reinterpret_cast<const f16x8*>(h2b + (rowR + ((64 + g * 16) ^ swzR)));
            const float xvt = x[tb + pt];          // 1 line, L1 broadcast
#pragma unroll
            for (int u = 0; u < 4; ++u) {
                f32x4 acc = { b3v[u][0], b3v[u][1], b3v[u][2], b3v[u][3] };
                acc = __builtin_amdgcn_mfma_f32_16x16x32_f16(a3[u][0], bb0, acc, 0, 0, 0);
                acc = __builtin_amdgcn_mfma_f32_16x16x32_f16(a3[u][1], bb1, acc, 0, 0, 0);
                // lane holds ch c = u*4+g (16B block) of local point r16:
                // bounce byte = r16*256 + ((c*16) ^ ((r16&7)<<4))
                float4 o4 = { acc[0] * xvt, acc[1] * xvt, acc[2] * xvt, acc[3] * xvt };
                const int wb = r16 * 256 + (((u * 64 + g * 16)) ^ ((r16 & 7) << 4));
                *reinterpret_cast<float4*>(stgb + wb) = o4;
            }
            // drain: 4 instructions, each one contiguous 1KB chunk (fill pattern)
            float* og = out + (size_t)(tb + t2 * 16) * 64;
#pragma unroll
            for (int k = 0; k < 4; ++k) {
                const int ptl = k * 4 + (lane >> 4);   // local point 0..15
                const int c   = lane & 15;             // 16B channel block
                const int rb  = ptl * 256 + ((c * 16) ^ ((ptl & 7) << 4));
                const float4 v = *reinterpret_cast<const float4*>(stgb + rb);
                *reinterpret_cast<float4*>(og + k * 256 + lane * 4) = v;
            }
        }
    }
}

extern "C" void kernel_launch(void* const* d_in, const int* in_sizes, int n_in,
                              void* d_out, int out_size, void* d_ws, size_t ws_size,
                              hipStream_t stream) {
    const float* x     = (const float*)d_in[0];
    const float* pos_i = (const float*)d_in[1];
    const float* pos_j = (const float*)d_in[2];
    const float* w11   = (const float*)d_in[3];
    const float* b11   = (const float*)d_in[4];
    const float* w12   = (const float*)d_in[5];
    const float* b12   = (const float*)d_in[6];
    const float* w13   = (const float*)d_in[7];
    const float* b13   = (const float*)d_in[8];
    float* out = (float*)d_out;

    const int n = in_sizes[0];                        // N (x is [N,1])
    const int per_block = 256 * TILES;                // 4 waves x 4 tiles x 64 pts
    const int blocks = (n + per_block - 1) / per_block;
    centershift_kernel<<<blocks, 256, 0, stream>>>(
        x, pos_i, pos_j, w11, b11, w12, b12, w13, b13, out, n);
}